// Round 6
// baseline (966.529 us; speedup 1.0000x reference)
//
#include <hip/hip_runtime.h>
#include <cstddef>
#include <cstdint>

// Problem constants
#define B_  4096
#define I_  512
#define L_  128
#define D_  512
#define E_  8
#define H_  512
#define HR_ 256
#define A_  32

typedef __attribute__((ext_vector_type(8))) __bf16 bf16x8;
typedef __attribute__((ext_vector_type(4))) __bf16 bf16x4;
typedef __attribute__((ext_vector_type(4))) float floatx4;

__device__ __forceinline__ float sigmoidf_(float x) { return 1.0f / (1.0f + __expf(-x)); }

__device__ __forceinline__ void load_lds16(const void* g, void* l) {
    __builtin_amdgcn_global_load_lds((__attribute__((address_space(1))) void*)g,
                                     (__attribute__((address_space(3))) void*)l, 16, 0, 0);
}

struct HiLo { __bf16 h, l; };
__device__ __forceinline__ HiLo hi_lo(float v) {
    HiLo r;
    r.h = (__bf16)v;
    r.l = (__bf16)(v - (float)r.h);
    return r;
}
__device__ __forceinline__ void split4(float4 v, bf16x4& hi, bf16x4& lo) {
    HiLo a = hi_lo(v.x), b = hi_lo(v.y), c = hi_lo(v.z), d = hi_lo(v.w);
    hi = (bf16x4){a.h, b.h, c.h, d.h};
    lo = (bf16x4){a.l, b.l, c.l, d.l};
}

// ---------------- unified prep kernel ----------------
__device__ __forceinline__ void wcat2_body(const float* __restrict__ W,
                                           __bf16* __restrict__ out, int i4, int K4) {
    int row = i4 / K4;
    int c4  = i4 - row * K4;
    const int K = K4 * 4;
    float4 v = ((const float4*)W)[i4];
    bf16x4 hi, lo;
    split4(v, hi, lo);
    __bf16* dst = out + (size_t)row * 2 * K + c4 * 4;
    *(bf16x4*)(dst)     = hi;
    *(bf16x4*)(dst + K) = lo;
}
__device__ __forceinline__ void f2b_body(const float* __restrict__ src,
                                         __bf16* __restrict__ dst, int i4) {
    float4 v = ((const float4*)src)[i4];
    bf16x4 o = { (__bf16)v.x, (__bf16)v.y, (__bf16)v.z, (__bf16)v.w };
    *(bf16x4*)(dst + (size_t)i4 * 4) = o;
}

// block segments (256 float4 per block):
//  [0,320)      W_in   wcat2 K4=160
//  [320,704)    Wih_r  wcat2 K4=128
//  [704,6848)   Wih_e  wcat2 K4=128
//  [6848,7040)  Whh_r  f2b
//  [7040,13184) Whh_e  f2b
//  [13184,15232) W_proj f2b
//  [15232,16256) h_r   f2b
__global__ __launch_bounds__(256) void prep_all(
    const float* __restrict__ W_in, const float* __restrict__ Wih_r,
    const float* __restrict__ Wih_e, const float* __restrict__ Whh_r,
    const float* __restrict__ Whh_e, const float* __restrict__ W_proj,
    const float* __restrict__ h_r,
    __bf16* __restrict__ W_in_hl, __bf16* __restrict__ Wih_r_hl,
    __bf16* __restrict__ Wih_e_hl, __bf16* __restrict__ Whh_r_b,
    __bf16* __restrict__ Whh_e_b, __bf16* __restrict__ W_proj_b,
    __bf16* __restrict__ hr_b)
{
    const int bid = blockIdx.x;
    const int tid = threadIdx.x;
    if (bid < 320)        wcat2_body(W_in,  W_in_hl,  bid * 256 + tid, 160);
    else if (bid < 704)   wcat2_body(Wih_r, Wih_r_hl, (bid - 320) * 256 + tid, 128);
    else if (bid < 6848)  wcat2_body(Wih_e, Wih_e_hl, (bid - 704) * 256 + tid, 128);
    else if (bid < 7040)  f2b_body(Whh_r,  Whh_r_b,  (bid - 6848) * 256 + tid);
    else if (bid < 13184) f2b_body(Whh_e,  Whh_e_b,  (bid - 7040) * 256 + tid);
    else if (bid < 15232) f2b_body(W_proj, W_proj_b, (bid - 13184) * 256 + tid);
    else                  f2b_body(h_r,    hr_b,     (bid - 15232) * 256 + tid);
}

// [x (B,512) | lang (B,128)] -> xcat (B,1920) = [hi | hi | lo]
__global__ __launch_bounds__(256) void concat_cat_k(const float* __restrict__ x,
                                                    const float* __restrict__ lang,
                                                    __bf16* __restrict__ out) {
    int idx = blockIdx.x * 256 + threadIdx.x;   // over B_*160 float4 groups
    int b = idx / 160;
    int c = idx - b * 160;
    float4 v;
    if (c < 128) v = ((const float4*)x)[(size_t)b * 128 + c];
    else         v = ((const float4*)lang)[(size_t)b * 32 + (c - 128)];
    bf16x4 hi, lo;
    split4(v, hi, lo);
    __bf16* dst = out + (size_t)b * 1920 + c * 4;
    *(bf16x4*)(dst)        = hi;
    *(bf16x4*)(dst + 640)  = hi;
    *(bf16x4*)(dst + 1280) = lo;
}

// h_e chunk convert: (E, B, H) fp32 rows [r0, r0+CH) -> (E, CH, H) bf16
__global__ __launch_bounds__(256) void f2bhe_k(const float* __restrict__ he,
                                               __bf16* __restrict__ dst,
                                               int r0, int chm /* CH*128 */) {
    int e  = blockIdx.y;
    int i4 = blockIdx.x * 256 + threadIdx.x;    // over CH*128
    int row = i4 >> 7;
    int c4  = i4 & 127;
    float4 v = ((const float4*)he)[(size_t)e * (B_ * 128) + (size_t)(r0 + row) * 128 + c4];
    bf16x4 o = { (__bf16)v.x, (__bf16)v.y, (__bf16)v.z, (__bf16)v.w };
    *(bf16x4*)(dst + ((size_t)e * chm + i4) * 4) = o;
}

// ---------------- MFMA GEMM ----------------
// acc = A[m,K] @ Bw[n,:]^T + bias[n], batched over blockIdx.z.
// B k-index wraps at kWrap; B row stride bRS.
// MODE 0: C fp32 = acc
// MODE 2: C fp32 = scale[m*sstride+z*szBatch] * acc
// MODE 4: C bf16 [hi|hi|lo] triple at row stride 1536 (xp_cat layout)
template<int MODE>
__global__ __launch_bounds__(256) void mgemm(
    const __bf16* __restrict__ A, long long aBatch,
    const __bf16* __restrict__ Bw, long long bBatch, int bRS, int kWrap,
    const float* __restrict__ bias, long long biasBatch,
    void* __restrict__ Cv, long long cBatch,
    int N, int K,
    const float* __restrict__ scale, int sstride, int szBatch)
{
    __shared__ __align__(16) __bf16 As[128 * 32];
    __shared__ __align__(16) __bf16 Bs[128 * 32];

    const int tid  = threadIdx.x;
    const int w    = tid >> 6;
    const int lane = tid & 63;
    const int m0 = blockIdx.x * 128;
    const int n0 = blockIdx.y * 128;
    const int z  = blockIdx.z;

    const int lrow = lane >> 2;
    const int lseg = lane & 3;
    const __bf16* Ag0 = A + (size_t)z * aBatch + (size_t)(m0 + w * 32 + lrow) * K + lseg * 8;
    const __bf16* Ag1 = Ag0 + (size_t)16 * K;
    const __bf16* Bg0 = Bw + (size_t)z * bBatch + (size_t)(n0 + w * 32 + lrow) * bRS + lseg * 8;
    const __bf16* Bg1 = Bg0 + (size_t)16 * bRS;
    __bf16* Al0 = As + (w * 32) * 32;
    __bf16* Al1 = Al0 + 16 * 32;
    __bf16* Bl0 = Bs + (w * 32) * 32;
    __bf16* Bl1 = Bl0 + 16 * 32;

    const int wm = w & 1, wn = w >> 1;
    const int lr16 = lane & 15;
    const int lq   = lane >> 4;
    const __bf16* Af = As + (wm * 64 + lr16) * 32 + lq * 8;
    const __bf16* Bf = Bs + (wn * 64 + lr16) * 32 + lq * 8;

    floatx4 acc[4][4];
#pragma unroll
    for (int i = 0; i < 4; ++i)
#pragma unroll
        for (int j = 0; j < 4; ++j) acc[i][j] = (floatx4){0.f, 0.f, 0.f, 0.f};

    for (int k0 = 0; k0 < K; k0 += 32) {
        const int kb = (k0 < kWrap) ? k0 : (k0 - kWrap);
        __syncthreads();
        load_lds16(Ag0 + k0, Al0);
        load_lds16(Ag1 + k0, Al1);
        load_lds16(Bg0 + kb, Bl0);
        load_lds16(Bg1 + kb, Bl1);
        __syncthreads();

        bf16x8 af[4], bfr[4];
#pragma unroll
        for (int t = 0; t < 4; ++t) {
            af[t]  = *(const bf16x8*)(Af + t * 16 * 32);
            bfr[t] = *(const bf16x8*)(Bf + t * 16 * 32);
        }
#pragma unroll
        for (int tm = 0; tm < 4; ++tm)
#pragma unroll
            for (int tn = 0; tn < 4; ++tn)
                acc[tm][tn] = __builtin_amdgcn_mfma_f32_16x16x32_bf16(af[tm], bfr[tn], acc[tm][tn], 0, 0, 0);
    }

    const float* biasz = bias + (size_t)z * biasBatch;
    const int sz = z * szBatch;
#pragma unroll
    for (int tm = 0; tm < 4; ++tm) {
        const int mbase = m0 + wm * 64 + tm * 16 + lq * 4;
#pragma unroll
        for (int r = 0; r < 4; ++r) {
            const int m = mbase + r;
            float wsc = 0.f;
            if (MODE == 2) wsc = scale[(size_t)m * sstride + sz];
#pragma unroll
            for (int tn = 0; tn < 4; ++tn) {
                const int n = n0 + wn * 64 + tn * 16 + lr16;
                float v = acc[tm][tn][r] + biasz[n];
                if (MODE == 0) {
                    ((float*)Cv)[(size_t)z * cBatch + (size_t)m * N + n] = v;
                } else if (MODE == 2) {
                    ((float*)Cv)[(size_t)z * cBatch + (size_t)m * N + n] = wsc * v;
                } else {  // MODE 4: xp_cat [hi|hi|lo], row stride 1536
                    HiLo s = hi_lo(v);
                    __bf16* xc = (__bf16*)Cv + (size_t)m * 1536 + n;
                    xc[0]    = s.h;
                    xc[512]  = s.h;
                    xc[1024] = s.l;
                }
            }
        }
    }
}

// ---------------- fully fused gates + GRU ----------------
// Per block: 128 rows x 64 h-cols, all 3 gates, K-loop over
// [xp_cat (K=1536, hi/lo) | h_prev_bf16 (K=HD)] vs [Wih_hl | Whh].
// r/z gates: single accumulator across the boundary (they only need gx+gh).
// n gate: separate gx / gh accumulators (n = tanh(gx_n + r*gh_n)).
template<int HD, bool WRITE_HNEW>
__global__ __launch_bounds__(256) void fgru2(
    const __bf16* __restrict__ Ax,                    // (rows,1536), shared over z
    const __bf16* __restrict__ Ah, long long ahB,     // (z,rows,HD) bf16
    const __bf16* __restrict__ Wih, long long wihB,   // (z,3HD,1024) [hi|lo]
    const __bf16* __restrict__ Whh, long long whhB,   // (z,3HD,HD)
    const float* __restrict__ bih, long long bihB,    // (z,3HD)
    const float* __restrict__ bhh, long long bhhB,    // (z,3HD)
    const float* __restrict__ hprev, long long hpB,   // (z,rows,HD) fp32
    float* __restrict__ hout, long long hoB,          // (z,rows,HD) fp32
    __bf16* __restrict__ hnew, long long hnB)         // (z,rows,HD) bf16
{
    constexpr int KX = 1536;
    __shared__ __align__(16) __bf16 As[128 * 32];
    __shared__ __align__(16) __bf16 Bs[192 * 32];

    const int tid  = threadIdx.x;
    const int w    = tid >> 6;
    const int lane = tid & 63;
    const int m0 = blockIdx.x * 128;
    const int j0 = blockIdx.y * 64;
    const int z  = blockIdx.z;

    const int lrow = lane >> 2;
    const int lseg = lane & 3;
    const int arow = m0 + w * 32 + lrow;
    const __bf16* Ax0 = Ax + (size_t)arow * 1536 + lseg * 8;
    const __bf16* Ax1 = Ax0 + (size_t)16 * 1536;
    const __bf16* Ah0 = Ah + (size_t)z * ahB + (size_t)arow * HD + lseg * 8;
    const __bf16* Ah1 = Ah0 + (size_t)16 * HD;
    __bf16* Al0 = As + (w * 32) * 32;
    __bf16* Al1 = Al0 + 16 * 32;

    // B: 192 rows = [r 64 | z 64 | n 64] for cols j0..j0+63
    const __bf16* Wihz = Wih + (size_t)z * wihB;
    const __bf16* Whhz = Whh + (size_t)z * whhB;
    const __bf16* Bgx[3];
    const __bf16* Bgh[3];
    __bf16* Bl[3];
#pragma unroll
    for (int i = 0; i < 3; ++i) {
        const int r = (w * 3 + i) * 16 + lrow;          // 0..191
        const int gate = r >> 6;
        const int grow = gate * HD + j0 + (r & 63);
        Bgx[i] = Wihz + (size_t)grow * 1024 + lseg * 8;
        Bgh[i] = Whhz + (size_t)grow * HD + lseg * 8;
        Bl[i]  = Bs + ((w * 3 + i) * 16) * 32;
    }

    const int mh = w & 1, nh = w >> 1;
    const int lr16 = lane & 15;
    const int lq   = lane >> 4;
    const __bf16* Af = As + (mh * 64 + lr16) * 32 + lq * 8;
    const __bf16* Bf = Bs + (nh * 32 + lr16) * 32 + lq * 8;

    floatx4 accr[4][2], accz[4][2], accnx[4][2], accnh[4][2];
#pragma unroll
    for (int i = 0; i < 4; ++i)
#pragma unroll
        for (int j = 0; j < 2; ++j) {
            accr[i][j]  = (floatx4){0.f, 0.f, 0.f, 0.f};
            accz[i][j]  = (floatx4){0.f, 0.f, 0.f, 0.f};
            accnx[i][j] = (floatx4){0.f, 0.f, 0.f, 0.f};
            accnh[i][j] = (floatx4){0.f, 0.f, 0.f, 0.f};
        }

    for (int k0 = 0; k0 < KX + HD; k0 += 32) {
        __syncthreads();
        if (k0 < KX) {
            const int kb = (k0 < 1024) ? k0 : (k0 - 1024);
            load_lds16(Ax0 + k0, Al0);
            load_lds16(Ax1 + k0, Al1);
#pragma unroll
            for (int i = 0; i < 3; ++i) load_lds16(Bgx[i] + kb, Bl[i]);
        } else {
            const int kh = k0 - KX;
            load_lds16(Ah0 + kh, Al0);
            load_lds16(Ah1 + kh, Al1);
#pragma unroll
            for (int i = 0; i < 3; ++i) load_lds16(Bgh[i] + kh, Bl[i]);
        }
        __syncthreads();

        bf16x8 af[4], br[2], bz[2], bn[2];
#pragma unroll
        for (int t = 0; t < 4; ++t) af[t] = *(const bf16x8*)(Af + t * 16 * 32);
#pragma unroll
        for (int tn = 0; tn < 2; ++tn) {
            br[tn] = *(const bf16x8*)(Bf + (0 * 64 + tn * 16) * 32);
            bz[tn] = *(const bf16x8*)(Bf + (1 * 64 + tn * 16) * 32);
            bn[tn] = *(const bf16x8*)(Bf + (2 * 64 + tn * 16) * 32);
        }
#pragma unroll
        for (int tm = 0; tm < 4; ++tm)
#pragma unroll
            for (int tn = 0; tn < 2; ++tn) {
                accr[tm][tn] = __builtin_amdgcn_mfma_f32_16x16x32_bf16(af[tm], br[tn], accr[tm][tn], 0, 0, 0);
                accz[tm][tn] = __builtin_amdgcn_mfma_f32_16x16x32_bf16(af[tm], bz[tn], accz[tm][tn], 0, 0, 0);
            }
        if (k0 < KX) {
#pragma unroll
            for (int tm = 0; tm < 4; ++tm)
#pragma unroll
                for (int tn = 0; tn < 2; ++tn)
                    accnx[tm][tn] = __builtin_amdgcn_mfma_f32_16x16x32_bf16(af[tm], bn[tn], accnx[tm][tn], 0, 0, 0);
        } else {
#pragma unroll
            for (int tm = 0; tm < 4; ++tm)
#pragma unroll
                for (int tn = 0; tn < 2; ++tn)
                    accnh[tm][tn] = __builtin_amdgcn_mfma_f32_16x16x32_bf16(af[tm], bn[tn], accnh[tm][tn], 0, 0, 0);
        }
    }

    const float* bihz = bih + (size_t)z * bihB;
    const float* bhhz = bhh + (size_t)z * bhhB;
#pragma unroll
    for (int tn = 0; tn < 2; ++tn) {
        const int j = j0 + nh * 32 + tn * 16 + lr16;
        const float br_ = bihz[j] + bhhz[j];
        const float bz_ = bihz[HD + j] + bhhz[HD + j];
        const float bnx = bihz[2 * HD + j];
        const float bnh = bhhz[2 * HD + j];
#pragma unroll
        for (int tm = 0; tm < 4; ++tm) {
#pragma unroll
            for (int rr = 0; rr < 4; ++rr) {
                const int row = m0 + mh * 64 + tm * 16 + lq * 4 + rr;
                float r  = sigmoidf_(accr[tm][tn][rr] + br_);
                float zz = sigmoidf_(accz[tm][tn][rr] + bz_);
                float n  = tanhf(accnx[tm][tn][rr] + bnx + r * (accnh[tm][tn][rr] + bnh));
                float hv = hprev[(size_t)z * hpB + (size_t)row * HD + j];
                float o  = (1.f - zz) * n + zz * hv;
                hout[(size_t)z * hoB + (size_t)row * HD + j] = o;
                if (WRITE_HNEW)
                    hnew[(size_t)z * hnB + (size_t)row * HD + j] = (__bf16)o;
            }
        }
    }
}

// ---------------- router fc + softmax ----------------
__global__ __launch_bounds__(256) void fc_softmax_k(const float* __restrict__ hr,
                                                    const float* __restrict__ Wfc,
                                                    const float* __restrict__ bfc,
                                                    float* __restrict__ wts) {
    int lane = threadIdx.x & 63;
    int wave = threadIdx.x >> 6;
    int rg = lane >> 3;
    int e  = lane & 7;
    int b  = blockIdx.x * 32 + wave * 8 + rg;
    const float* h = hr + (size_t)b * HR_;
    const float* w = Wfc + (size_t)e * HR_;
    float acc = 0.0f;
#pragma unroll 4
    for (int k = 0; k < HR_; k += 4) {
        float4 hv = *(const float4*)(h + k);
        float4 wv = *(const float4*)(w + k);
        acc += hv.x * wv.x + hv.y * wv.y + hv.z * wv.z + hv.w * wv.w;
    }
    acc += bfc[e];
    float m = acc;
    for (int off = 4; off; off >>= 1) m = fmaxf(m, __shfl_xor(m, off, 8));
    float ex = __expf(acc - m);
    float s = ex;
    for (int off = 4; off; off >>= 1) s += __shfl_xor(s, off, 8);
    wts[(size_t)b * E_ + e] = ex / s;
}

// ---------------- reduce 8 expert P planes (chunk) -> comb ----------------
__global__ __launch_bounds__(256) void reduce8_k(const float* __restrict__ P,
                                                 float* __restrict__ comb,
                                                 int n4, int ps4) {
    int i = blockIdx.x * 256 + threadIdx.x;
    if (i >= n4) return;
    float4 s = ((const float4*)P)[i];
#pragma unroll
    for (int e = 1; e < E_; ++e) {
        float4 v = ((const float4*)P)[i + (size_t)e * ps4];
        s.x += v.x; s.y += v.y; s.z += v.z; s.w += v.w;
    }
    ((float4*)comb)[i] = s;
}

// ---------------- head ----------------
__global__ __launch_bounds__(256) void head_k(const float* __restrict__ comb,
                                              const float* __restrict__ Wh,
                                              const float* __restrict__ bh,
                                              float* __restrict__ out) {
    __shared__ float hs[8][512];
    int b0 = blockIdx.x * 8;
    for (int i = threadIdx.x; i < 8 * 128; i += 256) {
        int rr = i >> 7, cc = i & 127;
        ((float4*)hs[rr])[cc] = ((const float4*)(comb + (size_t)(b0 + rr) * 512))[cc];
    }
    __syncthreads();
    int r = threadIdx.x >> 5, c = threadIdx.x & 31;
    const float* wrow = Wh + (size_t)c * 512;
    float acc = 0.f;
    for (int k = 0; k < 512; k += 4) {
        float4 wv = *(const float4*)(wrow + k);
        float4 hv = *(const float4*)(&hs[r][k]);
        acc += hv.x * wv.x + hv.y * wv.y + hv.z * wv.z + hv.w * wv.w;
    }
    out[(size_t)(b0 + r) * 32 + c] = acc + bh[c];
}

// ---------------- launcher ----------------
extern "C" void kernel_launch(void* const* d_in, const int* in_sizes, int n_in,
                              void* d_out, int out_size, void* d_ws, size_t ws_size,
                              hipStream_t stream)
{
    const float* x      = (const float*)d_in[0];
    const float* lang   = (const float*)d_in[1];
    const float* h_r    = (const float*)d_in[2];
    const float* h_e    = (const float*)d_in[3];
    const float* W_in   = (const float*)d_in[4];
    const float* b_in   = (const float*)d_in[5];
    const float* Wih_r  = (const float*)d_in[6];
    const float* Whh_r  = (const float*)d_in[7];
    const float* bih_r  = (const float*)d_in[8];
    const float* bhh_r  = (const float*)d_in[9];
    const float* W_fc   = (const float*)d_in[10];
    const float* b_fc   = (const float*)d_in[11];
    const float* Wih_e  = (const float*)d_in[12];
    const float* Whh_e  = (const float*)d_in[13];
    const float* bih_e  = (const float*)d_in[14];
    const float* bhh_e  = (const float*)d_in[15];
    const float* W_proj = (const float*)d_in[16];
    const float* b_proj = (const float*)d_in[17];
    const float* W_head = (const float*)d_in[18];
    const float* b_head = (const float*)d_in[19];

    float* out_logits = (float*)d_out;                 // B*A
    float* out_hr     = out_logits + (size_t)B_ * A_;  // B*HR
    float* out_he     = out_hr + (size_t)B_ * HR_;     // E*B*H

    char* wsb = (char*)d_ws;
    size_t off = 0;
    auto alloc = [&](size_t bytes) -> char* {
        char* p = wsb + off;
        off = (off + bytes + 255) & ~(size_t)255;
        return p;
    };

    // ---- persistent: 65.3 MB ----
    __bf16* Wih_e_hl = (__bf16*)alloc((size_t)12288 * 1024 * 2);   // [hi|lo]
    __bf16* Whh_e_b  = (__bf16*)alloc((size_t)8 * 1536 * 512 * 2);
    __bf16* W_proj_b = (__bf16*)alloc((size_t)8 * 512 * 512 * 2);
    __bf16* xp_cat   = (__bf16*)alloc((size_t)B_ * 1536 * 2);      // [hi|hi|lo]
    __bf16* W_in_hl  = (__bf16*)alloc((size_t)512 * 1280 * 2);
    __bf16* Wih_r_hl = (__bf16*)alloc((size_t)768 * 1024 * 2);
    __bf16* Whh_r_b  = (__bf16*)alloc((size_t)768 * 256 * 2);
    __bf16* hr_b     = (__bf16*)alloc((size_t)B_ * HR_ * 2);
    float*  wts      = (float*)alloc((size_t)B_ * E_ * 4);
    float*  comb     = (float*)alloc((size_t)B_ * D_ * 4);

    // ---- tier: full batch (CH=4096, ~203 MB) vs 2 chunks (CH=2048, ~136 MB) ----
    const bool full = ws_size >= (size_t)210 * 1024 * 1024;
    const int CH  = full ? B_ : (B_ / 2);
    const int NCH = B_ / CH;

    char* R = wsb + off;
    __bf16* xcat_cat = (__bf16*)R;                     // B*1920*2 = 15.7 MB (dead after inproj)
    const size_t hebB = (size_t)E_ * CH * H_ * 2;
    __bf16* heb   = (__bf16*)R;                        // overlaps xcat (sequenced)
    __bf16* henew = (__bf16*)(R + hebB);
    float*  P     = (float*)(R + 2 * hebB);            // E*CH*D*4

    // 1. all weight/state conversions in one dispatch
    prep_all<<<16256, 256, 0, stream>>>(W_in, Wih_r, Wih_e, Whh_r, Whh_e, W_proj, h_r,
                                        W_in_hl, Wih_r_hl, Wih_e_hl, Whh_r_b, Whh_e_b,
                                        W_proj_b, hr_b);
    // 2. concat + split input
    concat_cat_k<<<(B_ * 160) / 256, 256, 0, stream>>>(x, lang, xcat_cat);
    // 3. input projection -> xp_cat directly ([hi|hi|lo] epilogue)
    mgemm<4><<<dim3(32, 4, 1), 256, 0, stream>>>(xcat_cat, 0, W_in_hl, 0, 1280, 1280,
                                                 b_in, 0, xp_cat, 0, 512, 1920, nullptr, 0, 0);
    // 4. router: fused gates + GRU -> out_hr
    fgru2<HR_, false><<<dim3(32, 4, 1), 256, 0, stream>>>(
        xp_cat, hr_b, 0, Wih_r_hl, 0, Whh_r_b, 0,
        bih_r, 0, bhh_r, 0, h_r, 0, out_hr, 0, nullptr, 0);
    // 5. router fc + softmax -> wts
    fc_softmax_k<<<B_ / 32, 256, 0, stream>>>(out_hr, W_fc, b_fc, wts);

    // 6. experts
    for (int c = 0; c < NCH; ++c) {
        const int r0 = c * CH;
        f2bhe_k<<<dim3((CH * 128) / 256, E_, 1), 256, 0, stream>>>(h_e, heb, r0, CH * 128);
        fgru2<H_, true><<<dim3(CH / 128, 8, E_), 256, 0, stream>>>(
            xp_cat + (size_t)r0 * 1536,
            heb, (long long)CH * H_,
            Wih_e_hl, (long long)1536 * 1024,
            Whh_e_b, (long long)1536 * 512,
            bih_e, 3 * H_, bhh_e, 3 * H_,
            h_e + (size_t)r0 * H_, (long long)B_ * H_,
            out_he + (size_t)r0 * H_, (long long)B_ * H_,
            henew, (long long)CH * H_);
        mgemm<2><<<dim3(CH / 128, 4, E_), 256, 0, stream>>>(
            henew, (long long)CH * H_,
            W_proj_b, (long long)D_ * H_, 512, 512,
            b_proj, D_,
            P, (long long)CH * D_, D_, H_,
            wts + (size_t)r0 * E_, E_, 1);
        reduce8_k<<<(CH * 128) / 256, 256, 0, stream>>>(
            P, comb + (size_t)r0 * D_, CH * 128, CH * 128);
    }

    // 7. head
    head_k<<<B_ / 8, 256, 0, stream>>>(comb, W_head, b_head, out_logits);
}